// Round 2
// baseline (362.815 us; speedup 1.0000x reference)
//
#include <hip/hip_runtime.h>

#define RADIUS 8
#define LR 256
#define NC 24
#define GF_EPS 1e-4f

typedef float f4 __attribute__((ext_vector_type(4)));  // native vector: nontemporal-builtin legal

// ---------------- Kernel G: fully fused guided filter ----------------------------
// One block per (img, PAIR of LR rows k,k+1) -> 8 HR rows. grid = NC*128 = 3072.
// Instead of a separate LR pass writing A,B to global, each block RECOMPUTES the 4
// A,B source rows it needs (rows clamp(k-1..k+2)) straight from I_lr/p_lr, which are
// L2-resident (512 KB/image). The 8 I_hr float4 nontemporal loads are issued FIRST,
// so the whole LR recompute runs while the HBM reads are in flight.
// LDS: av/bv (8x256 x2 = 16 KB); the horizontal-tap double buffer is ALIASED into
// av[0..7] before av/bv are written (separated by a barrier), keeping LDS at 16 KB.
__global__ __launch_bounds__(256, 4) void kG(const float* __restrict__ p,
                                             const float* __restrict__ I,
                                             const float* __restrict__ Ihr,
                                             float* __restrict__ out) {
    __shared__ float av[8][LR];
    __shared__ float bv[8][LR];

    const int blk = blockIdx.x;
    const int img = blk >> 7;          // /128
    const int k2  = blk & 127;
    const int k   = k2 << 1;
    const int tx  = threadIdx.x;
    const int ib  = img * LR * LR;
    const float* Ii = I + ib;
    const float* pi = p + ib;

    // --- issue all 8 I_hr vector loads up-front: 128 B/thread in flight under recompute
    // HR row 4k has offset (4k)<<10 = k<<12 within the image.
    const long long base = ((long long)img << 20) + ((long long)k << 12) + (tx << 2);
    f4 ih[8];
    #pragma unroll
    for (int r = 0; r < 8; ++r)
        ih[r] = __builtin_nontemporal_load((const f4*)(Ihr + base + ((long long)r << 10)));

    // --- recompute A,B rows rows[j] = clamp(k-1+j, 0, 255), j=0..3 -----------------
    // vertical running window in registers; horizontal 17-tap via LDS (aliased in av)
    const int r0 = max(k - 1, 0);
    float sI = 0.f, sp_ = 0.f, sIp = 0.f, sII = 0.f;
    #pragma unroll 1
    for (int yy = r0 - RADIUS; yy <= r0 + RADIUS; ++yy) {
        if (yy >= 0 && yy < LR) {
            const float vi = Ii[yy * LR + tx];
            const float vq = pi[yy * LR + tx];
            sI += vi; sp_ += vq; sIp += vi * vq; sII += vi * vi;
        }
    }
    const int cntx = min(tx + RADIUS, LR - 1) - max(tx - RADIUS, 0) + 1;

    float a_[4], b_[4];
    int yprev = r0;
    #pragma unroll
    for (int j = 0; j < 4; ++j) {
        const int y = min(max(k - 1 + j, 0), LR - 1);
        if (y != yprev) {              // block-uniform; slides by exactly one row
            const int yadd = y + RADIUS;
            const int ysub = yprev - RADIUS;
            if (yadd < LR) {
                const float aI = Ii[yadd * LR + tx], aq = pi[yadd * LR + tx];
                sI += aI; sp_ += aq; sIp += aI * aq; sII += aI * aI;
            }
            if (ysub >= 0) {
                const float rI = Ii[ysub * LR + tx], rq = pi[ysub * LR + tx];
                sI -= rI; sp_ -= rq; sIp -= rI * rq; sII -= rI * rI;
            }
        }
        yprev = y;
        // tap staging aliased into av: rows {0,1}=vI {2,3}=vp {4,5}=vIp {6,7}=vII
        const int buf = j & 1;
        av[0 + buf][tx] = sI;
        av[2 + buf][tx] = sp_;
        av[4 + buf][tx] = sIp;
        av[6 + buf][tx] = sII;
        __syncthreads();
        // buf[j&1] is rewritten at j+2, which is after sync(j+1) -> race-free
        float hI = 0.f, hp = 0.f, hIp = 0.f, hII = 0.f;
        #pragma unroll
        for (int t = -RADIUS; t <= RADIUS; ++t) {
            const int   xt = tx + t;
            const int   xx = min(max(xt, 0), LR - 1);
            const float m  = ((unsigned)xt < (unsigned)LR) ? 1.f : 0.f;  // truncated window
            hI  = fmaf(m, av[0 + buf][xx], hI);
            hp  = fmaf(m, av[2 + buf][xx], hp);
            hIp = fmaf(m, av[4 + buf][xx], hIp);
            hII = fmaf(m, av[6 + buf][xx], hII);
        }
        const int   cnty = min(y + RADIUS, LR - 1) - max(y - RADIUS, 0) + 1;
        const float inv  = 1.0f / (float)(cntx * cnty);
        const float mI   = hI * inv;
        const float mp   = hp * inv;
        const float cov  = hIp * inv - mI * mp;
        const float var  = hII * inv - mI * mI;
        a_[j] = cov / (var + GF_EPS);
        b_[j] = mp - a_[j] * mI;
    }
    __syncthreads();   // all tap reads complete before av/bv are overwritten

    // --- vertical bilinear lerps (phase table), written once to LDS ----------------
    // a_[0]=row k-1(cl), a_[1]=row k, a_[2]=row k+1, a_[3]=row k+2(cl)
    av[0][tx] = a_[0] + 0.625f * (a_[1] - a_[0]);
    av[1][tx] = a_[0] + 0.875f * (a_[1] - a_[0]);
    av[2][tx] = a_[1] + 0.125f * (a_[2] - a_[1]);
    av[3][tx] = a_[1] + 0.375f * (a_[2] - a_[1]);
    av[4][tx] = a_[1] + 0.625f * (a_[2] - a_[1]);
    av[5][tx] = a_[1] + 0.875f * (a_[2] - a_[1]);
    av[6][tx] = a_[2] + 0.125f * (a_[3] - a_[2]);
    av[7][tx] = a_[2] + 0.375f * (a_[3] - a_[2]);
    bv[0][tx] = b_[0] + 0.625f * (b_[1] - b_[0]);
    bv[1][tx] = b_[0] + 0.875f * (b_[1] - b_[0]);
    bv[2][tx] = b_[1] + 0.125f * (b_[2] - b_[1]);
    bv[3][tx] = b_[1] + 0.375f * (b_[2] - b_[1]);
    bv[4][tx] = b_[1] + 0.625f * (b_[2] - b_[1]);
    bv[5][tx] = b_[1] + 0.875f * (b_[2] - b_[1]);
    bv[6][tx] = b_[2] + 0.125f * (b_[3] - b_[2]);
    bv[7][tx] = b_[2] + 0.375f * (b_[3] - b_[2]);
    __syncthreads();

    // --- horizontal lerps + fused A*I_hr + B, streamed out -------------------------
    const int cm1 = max(tx - 1, 0);
    const int cp1 = min(tx + 1, LR - 1);

    #pragma unroll
    for (int r = 0; r < 8; ++r) {
        const float am = av[r][cm1], ac = av[r][tx], ap = av[r][cp1];
        const float bm = bv[r][cm1], bc = bv[r][tx], bp = bv[r][cp1];
        float p0, p1, q0, q1;
        if (tx == 0) { p0 = ac; p1 = ac; q0 = bc; q1 = bc; }  // x<0 clamps to col 0
        else {
            p0 = am + 0.625f * (ac - am);
            p1 = am + 0.875f * (ac - am);
            q0 = bm + 0.625f * (bc - bm);
            q1 = bm + 0.875f * (bc - bm);
        }
        const float p2 = ac + 0.125f * (ap - ac);   // tx==255: ap==ac -> clamp ok
        const float p3 = ac + 0.375f * (ap - ac);
        const float q2 = bc + 0.125f * (bp - bc);
        const float q3 = bc + 0.375f * (bp - bc);

        f4 res;
        res.x = p0 * ih[r].x + q0;
        res.y = p1 * ih[r].y + q1;
        res.z = p2 * ih[r].z + q2;
        res.w = p3 * ih[r].w + q3;
        __builtin_nontemporal_store(res, (f4*)(out + base + ((long long)r << 10)));
    }
}

extern "C" void kernel_launch(void* const* d_in, const int* in_sizes, int n_in,
                              void* d_out, int out_size, void* d_ws, size_t ws_size,
                              hipStream_t stream) {
    const float* p_lr = (const float*)d_in[0];
    const float* I_lr = (const float*)d_in[1];
    const float* I_hr = (const float*)d_in[2];
    float* out = (float*)d_out;
    (void)d_ws; (void)ws_size;

    kG<<<NC * 128, 256, 0, stream>>>(p_lr, I_lr, I_hr, out);
}

// Round 4
// 205.962 us; speedup vs baseline: 1.7616x; 1.7616x over previous
//
#include <hip/hip_runtime.h>

#define RADIUS 8
#define LR 256
#define HRES 1024
#define NC 24
#define GF_EPS 1e-4f
#define FSTRIP 8   // output rows per block: grid = NC * (256/8) = 768 blocks

typedef float f4 __attribute__((ext_vector_type(4)));  // native vector: nontemporal-builtin legal

// ---------------- Kernel F: fused LR stage (vertical running sums + horizontal 17-tap + algebra)
// One block per (img, 8-row strip), 256 threads = one per column.
// Vertical box window is a per-thread register running sum; all 8 rows of the 4
// vertical-sum planes are staged to 32 KB LDS, then ONE barrier, then 8 tap-loops.
// (Round-1 version barriered once per row = 8 barriers; this is the same math with 1.)
// XCD swizzle: 768 blocks, chunk=96 -> each XCD owns 3 consecutive images, keeping the
// 1.5 MB I_lr/p_lr working set inside its 4 MiB L2 (round-2 lesson: without this, all
// 8 XCDs stream all 24 images and the "L2-resident" re-reads go to HBM).
__global__ __launch_bounds__(256) void kF(const float* __restrict__ p,
                                          const float* __restrict__ I,
                                          float* __restrict__ A, float* __restrict__ B) {
    __shared__ float s[FSTRIP][4][LR];   // [row][quantity: I,p,Ip,II][col] = 32 KB
    const int swz   = ((blockIdx.x & 7) * 96) + (blockIdx.x >> 3);  // bijective: 768%8==0
    const int x     = threadIdx.x;
    const int img   = swz >> 5;          // / 32 strips
    const int strip = swz & 31;
    const int y0    = strip * FSTRIP;
    const int ib    = img * LR * LR;
    const float* Ii = I + ib;
    const float* pi = p + ib;

    // warm-up: vertical sums over rows [y0-8, y0+8] (truncated at edges)
    float sI = 0.f, sp_ = 0.f, sIp = 0.f, sII = 0.f;
    #pragma unroll 1
    for (int yy = y0 - RADIUS; yy <= y0 + RADIUS; ++yy) {
        if (yy >= 0 && yy < LR) {
            const float vi = Ii[yy * LR + x];
            const float vq = pi[yy * LR + x];
            sI  += vi;
            sp_ += vq;
            sIp += vi * vq;
            sII += vi * vi;
        }
    }

    // stage all 8 rows' vertical sums, sliding the register window between rows
    #pragma unroll
    for (int k = 0; k < FSTRIP; ++k) {
        s[k][0][x] = sI;
        s[k][1][x] = sp_;
        s[k][2][x] = sIp;
        s[k][3][x] = sII;
        const int y    = y0 + k;
        const int yadd = y + RADIUS + 1;
        const int ysub = y - RADIUS;
        if (yadd < LR) {
            const float aI = Ii[yadd * LR + x], aq = pi[yadd * LR + x];
            sI += aI; sp_ += aq; sIp += aI * aq; sII += aI * aI;
        }
        if (ysub >= 0) {
            const float rI = Ii[ysub * LR + x], rq = pi[ysub * LR + x];
            sI -= rI; sp_ -= rq; sIp -= rI * rq; sII -= rI * rI;
        }
    }
    __syncthreads();   // the ONLY barrier

    const int cntx = min(x + RADIUS, LR - 1) - max(x - RADIUS, 0) + 1;
    #pragma unroll
    for (int k = 0; k < FSTRIP; ++k) {
        // horizontal 17-tap over the staged vertical sums (stride-1 LDS: conflict-free)
        float hI = 0.f, hp = 0.f, hIp = 0.f, hII = 0.f;
        #pragma unroll
        for (int t = -RADIUS; t <= RADIUS; ++t) {
            const int   xt = x + t;
            const int   xx = min(max(xt, 0), LR - 1);
            const float m  = ((unsigned)xt < (unsigned)LR) ? 1.f : 0.f;  // truncated window
            hI  = fmaf(m, s[k][0][xx], hI);
            hp  = fmaf(m, s[k][1][xx], hp);
            hIp = fmaf(m, s[k][2][xx], hIp);
            hII = fmaf(m, s[k][3][xx], hII);
        }
        const int   y    = y0 + k;
        const int   cnty = min(y + RADIUS, LR - 1) - max(y - RADIUS, 0) + 1;
        const float inv  = 1.0f / (float)(cntx * cnty);
        const float mI   = hI * inv;
        const float mp   = hp * inv;
        const float cov  = hIp * inv - mI * mp;
        const float var  = hII * inv - mI * mI;
        const float a    = cov / (var + GF_EPS);
        const float bb   = mp - a * mI;
        const int   idx  = ib + y * LR + x;
        A[idx] = a;
        B[idx] = bb;
    }
}

// ---------------- Kernel R: bilinear x4 upsample of A,B fused with A*I_hr + B -----
// One block per (img, PAIR of LR rows k,k+1) -> 8 HR rows. grid = NC*128 = 3072.
// Byte-identical to the round-1 (200 us) version except the XCD swizzle (chunk=384:
// each XCD owns 3 images -> A,B reads stay L2-local).
// Phase table (HR row 8*k2+r, k=2*k2), rows clamped to [0,255]:
//   r=0: lerp(A[k-1],A[k],.625)   r=1: .875
//   r=2: lerp(A[k],A[k+1],.125)   r=3: .375
//   r=4: lerp(A[k],A[k+1],.625)   r=5: .875
//   r=6: lerp(A[k+1],A[k+2],.125) r=7: .375
__global__ __launch_bounds__(256) void kR(const float* __restrict__ A, const float* __restrict__ B,
                                          const float* __restrict__ Ihr, float* __restrict__ out) {
    __shared__ float av[8][LR];
    __shared__ float bv[8][LR];

    const int swz = ((blockIdx.x & 7) * 384) + (blockIdx.x >> 3);  // bijective: 3072%8==0
    const int img = swz >> 7;          // /128
    const int k2  = swz & 127;
    const int k   = k2 << 1;
    const int tx  = threadIdx.x;

    const float* Ai = A + img * LR * LR;
    const float* Bi = B + img * LR * LR;
    const int rm = max(k - 1, 0);
    const int rp = min(k + 2, LR - 1);

    const float aU = Ai[rm * LR + tx];        // row k-1 (clamped)
    const float a0 = Ai[k * LR + tx];         // row k
    const float a1 = Ai[(k + 1) * LR + tx];   // row k+1
    const float aD = Ai[rp * LR + tx];        // row k+2 (clamped)
    const float bU = Bi[rm * LR + tx];
    const float b0 = Bi[k * LR + tx];
    const float b1 = Bi[(k + 1) * LR + tx];
    const float bD = Bi[rp * LR + tx];

    av[0][tx] = aU + 0.625f * (a0 - aU);
    av[1][tx] = aU + 0.875f * (a0 - aU);
    av[2][tx] = a0 + 0.125f * (a1 - a0);
    av[3][tx] = a0 + 0.375f * (a1 - a0);
    av[4][tx] = a0 + 0.625f * (a1 - a0);
    av[5][tx] = a0 + 0.875f * (a1 - a0);
    av[6][tx] = a1 + 0.125f * (aD - a1);
    av[7][tx] = a1 + 0.375f * (aD - a1);
    bv[0][tx] = bU + 0.625f * (b0 - bU);
    bv[1][tx] = bU + 0.875f * (b0 - bU);
    bv[2][tx] = b0 + 0.125f * (b1 - b0);
    bv[3][tx] = b0 + 0.375f * (b1 - b0);
    bv[4][tx] = b0 + 0.625f * (b1 - b0);
    bv[5][tx] = b0 + 0.875f * (b1 - b0);
    bv[6][tx] = b1 + 0.125f * (bD - b1);
    bv[7][tx] = b1 + 0.375f * (bD - b1);
    __syncthreads();

    // HR row 4k has offset (4k)<<10 = k<<12 within the image.
    const long long base = ((long long)img << 20) + ((long long)k << 12) + (tx << 2);

    f4 ih[8];
    #pragma unroll
    for (int r = 0; r < 8; ++r)
        ih[r] = __builtin_nontemporal_load((const f4*)(Ihr + base + ((long long)r << 10)));

    const int cm1 = max(tx - 1, 0);
    const int cp1 = min(tx + 1, LR - 1);

    #pragma unroll
    for (int r = 0; r < 8; ++r) {
        const float am = av[r][cm1], ac = av[r][tx], ap = av[r][cp1];
        const float bm = bv[r][cm1], bc = bv[r][tx], bp = bv[r][cp1];
        float p0, p1, q0, q1;
        if (tx == 0) { p0 = ac; p1 = ac; q0 = bc; q1 = bc; }  // x<0 clamps to col 0
        else {
            p0 = am + 0.625f * (ac - am);
            p1 = am + 0.875f * (ac - am);
            q0 = bm + 0.625f * (bc - bm);
            q1 = bm + 0.875f * (bc - bm);
        }
        const float p2 = ac + 0.125f * (ap - ac);   // tx==255: ap==ac -> clamp ok
        const float p3 = ac + 0.375f * (ap - ac);
        const float q2 = bc + 0.125f * (bp - bc);
        const float q3 = bc + 0.375f * (bp - bc);

        f4 res;
        res.x = p0 * ih[r].x + q0;
        res.y = p1 * ih[r].y + q1;
        res.z = p2 * ih[r].z + q2;
        res.w = p3 * ih[r].w + q3;
        __builtin_nontemporal_store(res, (f4*)(out + base + ((long long)r << 10)));
    }
}

extern "C" void kernel_launch(void* const* d_in, const int* in_sizes, int n_in,
                              void* d_out, int out_size, void* d_ws, size_t ws_size,
                              hipStream_t stream) {
    const float* p_lr = (const float*)d_in[0];
    const float* I_lr = (const float*)d_in[1];
    const float* I_hr = (const float*)d_in[2];
    float* out = (float*)d_out;
    float* ws  = (float*)d_ws;

    const int S = NC * LR * LR;   // 1,572,864 floats per plane
    float* A = ws + 0 * (size_t)S;
    float* B = ws + 1 * (size_t)S;

    kF<<<NC * (LR / FSTRIP), 256, 0, stream>>>(p_lr, I_lr, A, B);
    kR<<<NC * 128, 256, 0, stream>>>(A, B, I_hr, out);
}